// Round 15
// baseline (121.105 us; speedup 1.0000x reference)
//
#include <hip/hip_runtime.h>
#include <math.h>

// Problem constants
#define TT 16384   // tokens
#define HH 2048    // hidden
#define EE 64      // experts
#define KK 8       // top_k

#define TB 16          // tokens per block (one MFMA M-tile)
#define HC 64          // h per chunk (2 MFMA k-steps)
#define NCH (HH / HC)  // 32 chunks
#define KSPLIT 2       // K-slices (kernel A blocks per tile)
#define CPS (NCH / KSPLIT)  // 16 chunks per slice
#define TOPC 10        // fp32 candidate count for fixup
#define MARGIN_REL 8e-5f   // relative score margin (R14-validated)

// Output layout (flat float32):
// probs [TT][KK] | indices [TT][KK] | map [TT][EE] | aux scalar
#define IDX_OFF ((size_t)TT * KK)
#define MAP_OFF ((size_t)2 * TT * KK)
#define AUX_OFF ((size_t)2 * TT * KK + (size_t)TT * EE)

// d_ws: W planes (bf16 hi/lo, fragment-native, R10-validated) then partials.
// Partials: [tile*2+ks][tid][4] f32, 4 KB per A-block, coalesced.
#define WSPLANE 131072
#define PBUF_OFF (2 * WSPLANE)   // in shorts; byte offset 512 KB

typedef short bf16x8 __attribute__((ext_vector_type(8)));
typedef float f32x4  __attribute__((ext_vector_type(4)));

__device__ __forceinline__ unsigned short f2bf(float x) {   // RNE fp32->bf16
    unsigned int u = __float_as_uint(x);
    u += 0x7FFFu + ((u >> 16) & 1u);
    return (unsigned short)(u >> 16);
}
__device__ __forceinline__ float bf2f(unsigned short b) {
    return __uint_as_float(((unsigned int)b) << 16);
}
__device__ __forceinline__ void cvt4(const float4 v, ushort4* hi, ushort4* lo) {
    unsigned short h0 = f2bf(v.x), h1 = f2bf(v.y),
                   h2 = f2bf(v.z), h3 = f2bf(v.w);
    *hi = make_ushort4(h0, h1, h2, h3);
    *lo = make_ushort4(f2bf(v.x - bf2f(h0)), f2bf(v.y - bf2f(h1)),
                       f2bf(v.z - bf2f(h2)), f2bf(v.w - bf2f(h3)));
}

// ---- prep: gate_w fp32 -> bf16 hi/lo planes in fragment-native layout ----
__global__ __launch_bounds__(256)
void prep_kernel(const float* __restrict__ gw, unsigned short* __restrict__ ws)
{
    const int gid = blockIdx.x * 256 + threadIdx.x;
    const int e  = gid >> 9;
    const int k  = (gid & 511) * 4;
    float4 v = *(const float4*)(gw + (size_t)e * HH + k);
    ushort4 hi, lo;
    cvt4(v, &hi, &lo);
    const int off = (k >> 5) * 2048 + ((k >> 3) & 3) * 512 + e * 8 + (k & 7);
    *(ushort4*)(ws + off)           = hi;
    *(ushort4*)(ws + WSPLANE + off) = lo;
}

// ---- R14's validated chunk body (prefetch guard parameterized by climit) ----
#define CHUNKA(C, HV)                                                          \
  do {                                                                         \
    const unsigned short* bp_ = bBase + (size_t)(2 * (C)) * 2048;              \
    bf16x8 Bh0 = *(const bf16x8*)(bp_);                                        \
    bf16x8 Bl0 = *(const bf16x8*)(bp_ + WSPLANE);                              \
    bf16x8 Bh1 = *(const bf16x8*)(bp_ + 2048);                                 \
    bf16x8 Bl1 = *(const bf16x8*)(bp_ + 2048 + WSPLANE);                       \
    unsigned char* buf_ = smem + ((C) & 1) * 4096;                             \
    ushort4 hi_, lo_;                                                          \
    cvt4(HV, &hi_, &lo_);                                                      \
    *(ushort4*)(buf_ + hOff)        = hi_;                                     \
    *(ushort4*)(buf_ + 2048 + hOff) = lo_;                                     \
    __syncthreads();                                                           \
    if ((C) + 2 < climit) HV = *(const float4*)(hgp + ((C) + 2) * HC);         \
    bf16x8 Ah0 = *(const bf16x8*)(buf_ + aOff0);                               \
    bf16x8 Al0 = *(const bf16x8*)(buf_ + 2048 + aOff0);                        \
    bf16x8 Ah1 = *(const bf16x8*)(buf_ + aOff1);                               \
    bf16x8 Al1 = *(const bf16x8*)(buf_ + 2048 + aOff1);                        \
    acc = __builtin_amdgcn_mfma_f32_16x16x32_bf16(Ah0, Bl0, acc, 0, 0, 0);     \
    acc = __builtin_amdgcn_mfma_f32_16x16x32_bf16(Al0, Bh0, acc, 0, 0, 0);     \
    acc = __builtin_amdgcn_mfma_f32_16x16x32_bf16(Ah0, Bh0, acc, 0, 0, 0);     \
    acc = __builtin_amdgcn_mfma_f32_16x16x32_bf16(Ah1, Bl1, acc, 0, 0, 0);     \
    acc = __builtin_amdgcn_mfma_f32_16x16x32_bf16(Al1, Bh1, acc, 0, 0, 0);     \
    acc = __builtin_amdgcn_mfma_f32_16x16x32_bf16(Ah1, Bh1, acc, 0, 0, 0);     \
  } while (0)

// ---- kernel A: half-K GEMM partial, 2048 blocks (8/CU), 4 KB partial out ----
__global__ __launch_bounds__(256, 8)
void gemm_partial(const float* __restrict__ hidden,
                  const unsigned short* __restrict__ wsbuf,
                  float* __restrict__ pbuf)
{
    __shared__ __align__(16) unsigned char smem[8192];

    const int tid  = threadIdx.x;
    const int bid  = blockIdx.x;
    const int tile = bid >> 1;         // 0..1023
    const int ks   = bid & 1;          // K-slice
    const int tok0 = tile * TB;
    const int c0   = ks * CPS;
    const int climit = c0 + CPS;

    // staging coords (R14-validated)
    const int hr  = tid >> 4;
    const int hc4 = tid & 15;
    const float* hgp = hidden + (size_t)(tok0 + hr) * HH + hc4 * 4;
    const int hOff = hr * 128 + ((hc4 * 8) ^ ((hr & 7) << 4));

    // fragment coords (R14-validated)
    const int lane = tid & 63;
    const int e0   = (tid >> 6) * 16;
    const int rx   = lane & 15;
    const int kq   = lane >> 4;
    const int aOff0 = rx * 128 + ((kq * 16) ^ ((rx & 7) << 4));
    const int aOff1 = aOff0 ^ 64;
    const unsigned short* bBase = wsbuf + kq * 512 + (e0 + rx) * 8;

    f32x4 acc = {0.f, 0.f, 0.f, 0.f};

    float4 hvA = *(const float4*)(hgp + c0 * HC);
    float4 hvB = *(const float4*)(hgp + (c0 + 1) * HC);

    for (int c = c0; c < climit; c += 2) {
        CHUNKA(c, hvA);
        CHUNKA(c + 1, hvB);
    }

    // partial out: [bid][tid][4] f32 — fully coalesced 4 KB per block
    *(f32x4*)(pbuf + (size_t)bid * 1024 + tid * 4) = acc;
}

// ---- kernel B: sum partials + validated epilogue/fixup ----
__global__ __launch_bounds__(256, 4)
void reduce_epilogue(const float* __restrict__ hidden,
                     const float* __restrict__ gate_w,
                     const float* __restrict__ bias,
                     const float* __restrict__ pbuf,
                     float* __restrict__ out)
{
    __shared__ __align__(16) float lg[16 * 68 + 8];

    const int tid  = threadIdx.x;
    const int tile = blockIdx.x;       // 0..1023
    const int tok0 = tile * TB;

    f32x4 a0 = *(const f32x4*)(pbuf + (size_t)(tile * 2 + 0) * 1024 + tid * 4);
    f32x4 a1 = *(const f32x4*)(pbuf + (size_t)(tile * 2 + 1) * 1024 + tid * 4);
    f32x4 acc = a0 + a1;

    // fragment coords (same tid mapping as kernel A)
    const int lane = tid & 63;
    const int e0   = (tid >> 6) * 16;
    const int rx   = lane & 15;
    const int kq   = lane >> 4;

    #pragma unroll
    for (int r = 0; r < 4; ++r)
        lg[(4 * kq + r) * 68 + e0 + rx] = acc[r];
    __syncthreads();

    // ---- epilogue: 16 lanes per token (R14-validated verbatim) ----
    const int t   = tid >> 4;
    const int q   = tid & 15;
    const int tok = tok0 + t;

    float lv[4];
    #pragma unroll
    for (int i = 0; i < 4; ++i) lv[i] = lg[t * 68 + q + 16 * i];

    float mx = lv[0];
    #pragma unroll
    for (int i = 1; i < 4; ++i) mx = fmaxf(mx, lv[i]);
    #pragma unroll
    for (int sh = 1; sh < 16; sh <<= 1) mx = fmaxf(mx, __shfl_xor(mx, sh, 64));

    float ex[4], psum = 0.0f;
    #pragma unroll
    for (int i = 0; i < 4; ++i) { ex[i] = expf(lv[i] - mx); psum += ex[i]; }
    #pragma unroll
    for (int sh = 1; sh < 16; sh <<= 1) psum += __shfl_xor(psum, sh, 64);
    const float inv = 1.0f / psum;

    float pr[4], selv[4];
    #pragma unroll
    for (int i = 0; i < 4; ++i) {
        pr[i]   = ex[i] * inv;
        selv[i] = pr[i] + bias[q + 16 * i];
    }

    float ws_[TOPC], wp[TOPC];
    int   wi[TOPC];
    #pragma unroll
    for (int k = 0; k < TOPC; ++k) {
        float bs = selv[0], bp = pr[0];
        int bi = q;
        #pragma unroll
        for (int i = 1; i < 4; ++i)
            if (selv[i] > bs) { bs = selv[i]; bp = pr[i]; bi = q + 16 * i; }
        #pragma unroll
        for (int sh = 1; sh < 16; sh <<= 1) {
            float os = __shfl_xor(bs, sh, 64);
            float op = __shfl_xor(bp, sh, 64);
            int   ob = __shfl_xor(bi, sh, 64);
            if (os > bs || (os == bs && ob < bi)) { bs = os; bp = op; bi = ob; }
        }
        ws_[k] = bs; wp[k] = bp; wi[k] = bi;
        #pragma unroll
        for (int i = 0; i < 4; ++i)
            if (q + 16 * i == bi) selv[i] = -INFINITY;
    }

    bool flag = false;
    #pragma unroll
    for (int k = 0; k < 8; ++k)
        flag = flag || (ws_[k] - ws_[k + 1] <
                        (ws_[k] + ws_[k + 1]) * MARGIN_REL + 1e-12f);

    if (flag) {
        const float* hrow = hidden + (size_t)tok * HH;
        const float* wr_[TOPC];
        #pragma unroll
        for (int k = 0; k < TOPC; ++k) wr_[k] = gate_w + (size_t)wi[k] * HH;

        double l64[TOPC];
        #pragma unroll
        for (int k = 0; k < TOPC; ++k) l64[k] = 0.0;

        for (int m = 0; m < 32; ++m) {
            float4 h4 = *(const float4*)(hrow + m * 64 + 4 * q);
            double h0 = h4.x, h1 = h4.y, h2 = h4.z, h3 = h4.w;
            #pragma unroll
            for (int k = 0; k < TOPC; ++k) {
                float4 w4 = *(const float4*)(wr_[k] + m * 64 + 4 * q);
                l64[k] = fma(h0, (double)w4.x, l64[k]);
                l64[k] = fma(h1, (double)w4.y, l64[k]);
                l64[k] = fma(h2, (double)w4.z, l64[k]);
                l64[k] = fma(h3, (double)w4.w, l64[k]);
            }
        }
        #pragma unroll
        for (int k = 0; k < TOPC; ++k)
            #pragma unroll
            for (int sh = 1; sh < 16; sh <<= 1)
                l64[k] += __shfl_xor(l64[k], sh, 64);

        double s64[TOPC];
        #pragma unroll
        for (int k = 0; k < TOPC; ++k)
            s64[k] = exp(l64[k] - (double)mx) * (double)inv + (double)bias[wi[k]];

        #pragma unroll
        for (int a = 0; a < 8; ++a) {
            #pragma unroll
            for (int b = a + 1; b < TOPC; ++b) {
                bool sw = (s64[b] > s64[a]) ||
                          (s64[b] == s64[a] && wi[b] < wi[a]);
                if (sw) {
                    double td = s64[a]; s64[a] = s64[b]; s64[b] = td;
                    int    ti = wi[a];  wi[a]  = wi[b];  wi[b]  = ti;
                    float  tp = wp[a];  wp[a]  = wp[b];  wp[b]  = tp;
                }
            }
        }
    }

    int oi = wi[0];
    float opf = wp[0];
    #pragma unroll
    for (int k = 1; k < 8; ++k)
        if (q == k) { oi = wi[k]; opf = wp[k]; }

    float ps = 0.0f;
    #pragma unroll
    for (int k = 0; k < 8; ++k) ps += wp[k];
    const float rinv = 1.0f / (ps + 1e-9f);

    if (q < KK) {
        out[(size_t)tok * KK + q]           = opf * rinv;
        out[IDX_OFF + (size_t)tok * KK + q] = (float)oi;
    }

    unsigned long long mk = 0ull;
    #pragma unroll
    for (int k = 0; k < 8; ++k) mk |= (1ull << wi[k]);

    {
        float4 a;
        a.x = ((mk >> (4 * q + 0)) & 1ull) ? 1.0f : 0.0f;
        a.y = ((mk >> (4 * q + 1)) & 1ull) ? 1.0f : 0.0f;
        a.z = ((mk >> (4 * q + 2)) & 1ull) ? 1.0f : 0.0f;
        a.w = ((mk >> (4 * q + 3)) & 1ull) ? 1.0f : 0.0f;
        *(float4*)(out + MAP_OFF + (size_t)tok * EE + 4 * q) = a;
    }

    if (blockIdx.x == 0 && tid == 0) out[AUX_OFF] = 0.0f;
}

extern "C" void kernel_launch(void* const* d_in, const int* in_sizes, int n_in,
                              void* d_out, int out_size, void* d_ws, size_t ws_size,
                              hipStream_t stream) {
    const float* hidden = (const float*)d_in[0];  // [16384, 2048] f32
    const float* gate_w = (const float*)d_in[1];  // [64, 2048] f32
    const float* bias   = (const float*)d_in[2];  // [64] f32
    float* out = (float*)d_out;
    unsigned short* ws = (unsigned short*)d_ws;   // needs 512 KB + 8 MB
    float* pbuf = (float*)(ws + PBUF_OFF);

    prep_kernel<<<128, 256, 0, stream>>>(gate_w, ws);
    gemm_partial<<<(TT / TB) * KSPLIT, 256, 0, stream>>>(hidden, ws, pbuf);
    reduce_epilogue<<<TT / TB, 256, 0, stream>>>(hidden, gate_w, bias, pbuf, out);
}